// Round 7
// baseline (2005.965 us; speedup 1.0000x reference)
//
#include <hip/hip_runtime.h>
#include <cstdint>
#include <cstddef>

#define B_ 2
#define T_ 4096
#define D_ 2048
#define H_ 8
#define DK_ 128
#define DV_ 256
#define BT_ (B_*T_)
#define NQK_ 1024
#define NV_ 2048
#define N1_ 6144   // packed: q[0,1024) k[1024,2048) v[2048,4096) gate[4096,6144)

typedef __bf16 bf16x8 __attribute__((ext_vector_type(8)));
typedef float f32x4 __attribute__((ext_vector_type(4)));

#define GAS __attribute__((address_space(1)))
#define LAS __attribute__((address_space(3)))

__device__ __forceinline__ float bfu(unsigned short u) {
  union { unsigned int i; float f; } c; c.i = ((unsigned int)u) << 16; return c.f;
}
__device__ __forceinline__ float bflo(unsigned int u) {
  union { unsigned int i; float f; } c; c.i = u << 16; return c.f;
}
__device__ __forceinline__ float bfhi(unsigned int u) {
  union { unsigned int i; float f; } c; c.i = u & 0xFFFF0000u; return c.f;
}
__device__ __forceinline__ unsigned short f2bf(float f) {
  union { float f; unsigned int i; } c; c.f = f;
  unsigned int x = c.i;
  x += 0x7FFFu + ((x >> 16) & 1u);
  return (unsigned short)(x >> 16);
}
__device__ __forceinline__ unsigned int pack2(float a, float b) {
  return (unsigned int)f2bf(a) | ((unsigned int)f2bf(b) << 16);
}
__device__ __forceinline__ float siluf(float x) { return x / (1.f + __expf(-x)); }
__device__ __forceinline__ float redsum32(float v) {
  #pragma unroll
  for (int m = 16; m >= 1; m >>= 1) v += __shfl_xor(v, m);
  return v;
}
__device__ __forceinline__ void async_copy16(void* lds, const void* gsrc) {
  __builtin_amdgcn_global_load_lds((const GAS unsigned int*)gsrc,
                                   (LAS unsigned int*)lds, 16, 0, 0);
}

// ---- DPP helpers ----
template<int CTRL>
__device__ __forceinline__ float dpp_add(float x) {
  union { int i; float f; } a, r;
  a.f = x;
  r.i = __builtin_amdgcn_update_dpp(0, a.i, CTRL, 0xF, 0xF, true);
  return x + r.f;
}
// rotate-based reduction within each 16-lane row: EVERY lane gets the row sum
__device__ __forceinline__ float red16_ror(float x) {
  x = dpp_add<0x121>(x);   // row_ror:1
  x = dpp_add<0x122>(x);   // row_ror:2
  x = dpp_add<0x124>(x);   // row_ror:4
  x = dpp_add<0x128>(x);   // row_ror:8
  return x;
}

// ---------------- cast x (f32 -> bf16) ----------------
__global__ __launch_bounds__(256) void cast_x_kernel(const float* __restrict__ in,
                                                     unsigned short* __restrict__ out) {
  size_t i = ((size_t)blockIdx.x * 256 + threadIdx.x) * 4;
  float4 v = *(const float4*)(in + i);
  uint2 r;
  r.x = pack2(v.x, v.y);
  r.y = pack2(v.z, v.w);
  *(uint2*)(out + i) = r;
}

// ---------------- transpose + cast weight (f32 [R][C] -> bf16 [C][R]) ----------------
__global__ __launch_bounds__(256) void transpose_cast(const float* __restrict__ in,
                                                      unsigned short* __restrict__ out,
                                                      int R, int Cc) {
  __shared__ float tile[32][33];
  int c0 = blockIdx.x * 32, r0 = blockIdx.y * 32;
  int tx = threadIdx.x, ty = threadIdx.y;  // (32,8)
  #pragma unroll
  for (int i = 0; i < 4; ++i)
    tile[ty + i*8][tx] = in[(size_t)(r0 + ty + i*8) * Cc + c0 + tx];
  __syncthreads();
  #pragma unroll
  for (int i = 0; i < 4; ++i)
    out[(size_t)(c0 + ty + i*8) * R + r0 + tx] = f2bf(tile[tx][ty + i*8]);
}

// ---------------- bf16 MFMA GEMM: C[M,N] = A[M,K] * Bt[N,K]^T ----------------
template<int BF16OUT>
__global__ __launch_bounds__(256) void gemm_kernel(
    const unsigned short* __restrict__ A,   // [M][K] bf16
    const unsigned short* __restrict__ Bt,  // [N][K] bf16
    void* __restrict__ Cout,
    int M, int N, int K)
{
  __shared__ __align__(16) unsigned short As[128][32];
  __shared__ __align__(16) unsigned short Bs[128][32];
  const int tid  = threadIdx.x;
  const int lane = tid & 63;
  const int wave = tid >> 6;
  const int wr = wave >> 1, wc = wave & 1;
  const int row0 = blockIdx.y * 128, col0 = blockIdx.x * 128;
  f32x4 acc[4][4];
  #pragma unroll
  for (int m = 0; m < 4; ++m)
    #pragma unroll
    for (int n = 0; n < 4; ++n)
      acc[m][n] = (f32x4){0.f, 0.f, 0.f, 0.f};

  const int fr = lane & 15;   // row within 16x16 frag
  const int fq = lane >> 4;   // k-quad (8 contiguous k per lane)

  for (int k0 = 0; k0 < K; k0 += 32) {
    #pragma unroll
    for (int i = 0; i < 2; ++i) {
      int c = tid + i * 256;          // chunk id 0..511 -> LDS byte c*16 (linear)
      int r = c >> 2, o = (c & 3) * 8;
      async_copy16(&As[r][o], A  + (size_t)(row0 + r) * K + k0 + o);
      async_copy16(&Bs[r][o], Bt + (size_t)(col0 + r) * K + k0 + o);
    }
    asm volatile("s_waitcnt vmcnt(0)" ::: "memory");
    __syncthreads();
    bf16x8 af[4], bfr[4];
    #pragma unroll
    for (int m = 0; m < 4; ++m)
      af[m] = *(const bf16x8*)&As[wr*64 + m*16 + fr][fq*8];
    #pragma unroll
    for (int n = 0; n < 4; ++n)
      bfr[n] = *(const bf16x8*)&Bs[wc*64 + n*16 + fr][fq*8];
    #pragma unroll
    for (int m = 0; m < 4; ++m)
      #pragma unroll
      for (int n = 0; n < 4; ++n)
        acc[m][n] = __builtin_amdgcn_mfma_f32_16x16x32_bf16(af[m], bfr[n], acc[m][n], 0, 0, 0);
    __syncthreads();
  }
  // C/D layout: col = lane&15, row = (lane>>4)*4 + reg
  const int fc = lane & 15, fg = lane >> 4;
  #pragma unroll
  for (int m = 0; m < 4; ++m)
    #pragma unroll
    for (int n = 0; n < 4; ++n)
      #pragma unroll
      for (int r = 0; r < 4; ++r) {
        size_t idx = (size_t)(row0 + wr*64 + m*16 + fg*4 + r) * N
                   + (col0 + wc*64 + n*16 + fc);
        if (BF16OUT) ((unsigned short*)Cout)[idx] = f2bf(acc[m][n][r]);
        else         ((float*)Cout)[idx]          = acc[m][n][r];
      }
}

// ---------------- beta / gamma projection (f32, N=16) ----------------
// Stores interleaved (beta, gamma=exp(g)) pairs so delta does ONE float2 load
// per step and has no transcendental on its critical path.
__global__ __launch_bounds__(256) void beta_g_kernel(
    const float* __restrict__ x, const float* __restrict__ Wb, const float* __restrict__ Wa,
    const float* __restrict__ A_log, const float* __restrict__ dtb,
    float* __restrict__ bg)
{
  const int t = blockIdx.x;
  const int wave = threadIdx.x >> 6;
  const int lane = threadIdx.x & 63;
  const float* xr = x + (size_t)t * D_;
  float acc[4] = {0.f, 0.f, 0.f, 0.f};
  for (int k = lane; k < D_; k += 64) {
    float xv = xr[k];
    #pragma unroll
    for (int i = 0; i < 4; ++i) {
      int o = wave + 4 * i;                 // 0..7: beta heads, 8..15: a heads
      float w = (o < 8) ? Wb[(size_t)k * 8 + o] : Wa[(size_t)k * 8 + (o - 8)];
      acc[i] += xv * w;
    }
  }
  #pragma unroll
  for (int i = 0; i < 4; ++i) {
    #pragma unroll
    for (int m = 32; m >= 1; m >>= 1) acc[i] += __shfl_xor(acc[i], m);
  }
  if (lane == 0) {
    #pragma unroll
    for (int i = 0; i < 4; ++i) {
      int o = wave + 4 * i;
      if (o < 8) {
        bg[((size_t)t * H_ + o) * 2] = 1.f / (1.f + __expf(-acc[i]));
      } else {
        int h = o - 8;
        float z = acc[i] + dtb[h];
        float sp = (z > 20.f) ? z : log1pf(__expf(z));
        bg[((size_t)t * H_ + h) * 2 + 1] = __expf(-__expf(A_log[h]) * sp);
      }
    }
  }
}

// ---------------- causal dwconv(W=4) + silu + l2norm ----------------
__global__ __launch_bounds__(256) void conv_kernel(
    const unsigned short* __restrict__ Y1,
    const float* __restrict__ cq, const float* __restrict__ ck, const float* __restrict__ cv,
    float* __restrict__ qf, float* __restrict__ kf, float* __restrict__ vf)
{
  const int t  = blockIdx.x;          // global row (b*T + tt)
  const int tt = t & (T_ - 1);
  const int tid = threadIdx.x;
  const int c4 = tid * 4;
  const int c8 = tid * 8;

  float wqa[4][4], wka[4][4], wva[8][4];
  #pragma unroll
  for (int m = 0; m < 4; ++m) {
    float4 a = *(const float4*)(cq + (size_t)(c4 + m) * 4);
    wqa[m][0] = a.x; wqa[m][1] = a.y; wqa[m][2] = a.z; wqa[m][3] = a.w;
    float4 b = *(const float4*)(ck + (size_t)(c4 + m) * 4);
    wka[m][0] = b.x; wka[m][1] = b.y; wka[m][2] = b.z; wka[m][3] = b.w;
  }
  #pragma unroll
  for (int m = 0; m < 8; ++m) {
    float4 a = *(const float4*)(cv + (size_t)(c8 + m) * 4);
    wva[m][0] = a.x; wva[m][1] = a.y; wva[m][2] = a.z; wva[m][3] = a.w;
  }

  float aq[4] = {0,0,0,0}, ak[4] = {0,0,0,0}, av[8] = {0,0,0,0,0,0,0,0};
  #pragma unroll
  for (int i = 0; i < 4; ++i) {
    if (tt + i >= 3) {      // tap i reads x[t-3+i]
      const unsigned short* row = Y1 + (size_t)(t + i - 3) * N1_;
      ushort4 yq = *(const ushort4*)(row + c4);
      ushort4 yk = *(const ushort4*)(row + NQK_ + c4);
      int4    yv = *(const int4*)(row + 2 * NQK_ + c8);
      float qv[4] = { bfu(yq.x), bfu(yq.y), bfu(yq.z), bfu(yq.w) };
      float kv[4] = { bfu(yk.x), bfu(yk.y), bfu(yk.z), bfu(yk.w) };
      unsigned int vu[4] = { (unsigned)yv.x, (unsigned)yv.y, (unsigned)yv.z, (unsigned)yv.w };
      float vv[8] = { bflo(vu[0]), bfhi(vu[0]), bflo(vu[1]), bfhi(vu[1]),
                      bflo(vu[2]), bfhi(vu[2]), bflo(vu[3]), bfhi(vu[3]) };
      #pragma unroll
      for (int m = 0; m < 4; ++m) { aq[m] += qv[m] * wqa[m][i]; ak[m] += kv[m] * wka[m][i]; }
      #pragma unroll
      for (int m = 0; m < 8; ++m) av[m] += vv[m] * wva[m][i];
    }
  }
  float sq[4], sk[4], ssq = 0.f, ssk = 0.f;
  #pragma unroll
  for (int m = 0; m < 4; ++m) {
    sq[m] = siluf(aq[m]); ssq += sq[m] * sq[m];
    sk[m] = siluf(ak[m]); ssk += sk[m] * sk[m];
  }
  ssq = redsum32(ssq);   // head = tid/32; 32-lane groups align with heads
  ssk = redsum32(ssk);
  float scq = rsqrtf(ssq + 1e-6f) * 0.08838834764831845f;  // * DK^-0.5
  float sck = rsqrtf(ssk + 1e-6f);
  float4 oq = { sq[0]*scq, sq[1]*scq, sq[2]*scq, sq[3]*scq };
  float4 ok = { sk[0]*sck, sk[1]*sck, sk[2]*sck, sk[3]*sck };
  *(float4*)(qf + (size_t)t * NQK_ + c4) = oq;
  *(float4*)(kf + (size_t)t * NQK_ + c4) = ok;
  float4 ov0 = { siluf(av[0]), siluf(av[1]), siluf(av[2]), siluf(av[3]) };
  float4 ov1 = { siluf(av[4]), siluf(av[5]), siluf(av[6]), siluf(av[7]) };
  *(float4*)(vf + (size_t)t * NV_ + c8)     = ov0;
  *(float4*)(vf + (size_t)t * NV_ + c8 + 4) = ov1;
}

// ---------------- gated delta-rule recurrence ----------------
// 16-lane groups, 8 state elems/lane, 4 DV-columns/wave, 1024 blocks.
// Memory strategy (round-7):
//  * v/beta/gamma staged into LDS via global_load_lds, 8-slot ring, issued 7
//    tiles (56 rows) ahead — prefetch depth lives in the vmcnt queue, not
//    VGPRs, so the compiler cannot collapse it (rounds 5/6 failure mode).
//    One width-4 issue per 8-row tile: lanes 0-31 carry v (8 rows x 4 cols),
//    lanes 32-47 carry (beta,gamma) pairs, lanes 48-63 dummy.
//    Tile-top `s_waitcnt vmcnt(15)`: VMEM retires in order; at every tile c
//    >=15 VMEM ops were issued after stage(c) (min exactly 15 at c=0), so
//    outstanding<=15 proves stage(c) landed, while the 7 newer stages are
//    never waited on.
//  * q/k stay register loads at distance 2 (4 slots), pinned by
//    asm volatile("" ::: "memory") between PREF and STEP — memory clobber
//    blocks IR-level load sinking, which sched_barrier(0) did not.
// Over-read audit: q/k rows to T+1 (qf->kf, kf->vf); v/bg stages stop at the
// last tile (guarded). o aliases vf: reads run >=1 row (v: >=49 rows) ahead
// of the store row; columns disjoint across waves.
__global__ __launch_bounds__(64, 1) void delta_kernel(
    const float* __restrict__ qf, const float* __restrict__ kf,
    const float* __restrict__ vf, const float* __restrict__ bg,
    float* __restrict__ o)
{
  __shared__ float vbg_lds[8 * 64];   // 8 slots x 256B

  const int blk = blockIdx.x;
  const int bh = blk & 15;     // fastest-varying -> same bh clusters per XCD
  const int jq = blk >> 4;     // 0..63 column quad
  const int b = bh >> 3, h = bh & 7;
  const int lane = threadIdx.x;
  const int r = lane & 15;
  const int g = lane >> 4;     // group = column index within quad
  const int j0 = jq * 4;

  const int SQK = H_ * DK_;    // 1024
  const int SV  = H_ * DV_;    // 2048

  const float* qp = qf + (size_t)(b * T_) * SQK + h * DK_ + r * 8;
  const float* kp = kf + (size_t)(b * T_) * SQK + h * DK_ + r * 8;
  float*       op = o  + (size_t)(b * T_) * SV + h * DV_ + j0 + g;

  // per-lane staging source (v for lanes 0-31, beta/gamma for 32-47, dummy 48-63)
  const float* stgsrc;
  int stgstep;
  if (lane < 32) {
    stgsrc = vf + ((size_t)(b * T_) + (lane >> 2)) * SV + h * DV_ + j0 + (lane & 3);
    stgstep = 8 * SV;
  } else {
    int l2 = (lane - 32) & 15;
    stgsrc = bg + ((size_t)(b * T_) + (l2 >> 1)) * (H_ * 2) + h * 2 + (l2 & 1);
    stgstep = 8 * H_ * 2;
  }

  float4 Sa = {0,0,0,0}, Sb = {0,0,0,0};
  float4 ka0,kb0,qa0,qb0, ka1,kb1,qa1,qb1, ka2,kb2,qa2,qb2, ka3,kb3,qa3,qb3;

#define STAGE(SLOT) do { \
    __builtin_amdgcn_global_load_lds((const GAS unsigned int*)stgsrc, \
        (LAS unsigned int*)(vbg_lds + (SLOT) * 64), 4, 0, 0); \
    stgsrc += stgstep; \
  } while (0)

#define PREFQK(SL, ROW) do { \
    ka##SL = *(const float4*)(kp + (ROW) * SQK); \
    kb##SL = *(const float4*)(kp + (ROW) * SQK + 4); \
    qa##SL = *(const float4*)(qp + (ROW) * SQK); \
    qb##SL = *(const float4*)(qp + (ROW) * SQK + 4); \
  } while (0)

#define FENCE asm volatile("" ::: "memory")

#define STEPX(SL, RT) do { \
    float vvx = vbg_lds[sofs + (RT) * 4 + g]; \
    float2 bgv = *(const float2*)&vbg_lds[sofs + 32 + (RT) * 2]; \
    float p0 = ka##SL.x*Sa.x, p1 = ka##SL.y*Sa.y, p2 = ka##SL.z*Sa.z, p3 = ka##SL.w*Sa.w; \
    float p4 = kb##SL.x*Sb.x, p5 = kb##SL.y*Sb.y, p6 = kb##SL.z*Sb.z, p7 = kb##SL.w*Sb.w; \
    float part = ((p0 + p1) + (p2 + p3)) + ((p4 + p5) + (p6 + p7)); \
    float dot = red16_ror(part); \
    float gm = bgv.y; \
    float u = bgv.x * fmaf(-gm, dot, vvx); \
    Sa.x = fmaf(gm, Sa.x, ka##SL.x * u); \
    Sa.y = fmaf(gm, Sa.y, ka##SL.y * u); \
    Sa.z = fmaf(gm, Sa.z, ka##SL.z * u); \
    Sa.w = fmaf(gm, Sa.w, ka##SL.w * u); \
    Sb.x = fmaf(gm, Sb.x, kb##SL.x * u); \
    Sb.y = fmaf(gm, Sb.y, kb##SL.y * u); \
    Sb.z = fmaf(gm, Sb.z, kb##SL.z * u); \
    Sb.w = fmaf(gm, Sb.w, kb##SL.w * u); \
    float o0 = qa##SL.x*Sa.x, o1 = qa##SL.y*Sa.y, o2 = qa##SL.z*Sa.z, o3 = qa##SL.w*Sa.w; \
    float o4 = qb##SL.x*Sb.x, o5 = qb##SL.y*Sb.y, o6 = qb##SL.z*Sb.z, o7 = qb##SL.w*Sb.w; \
    float pov = ((o0 + o1) + (o2 + o3)) + ((o4 + o5) + (o6 + o7)); \
    float od = red16_ror(pov); \
    if (r == 0) *op = od; \
    op += SV; \
  } while (0)

  const int NTILES = T_ / 8;   // 512

  // prologue: stage tiles 0..6, preload q/k rows 0,1
  STAGE(0); STAGE(1); STAGE(2); STAGE(3); STAGE(4); STAGE(5); STAGE(6);
  PREFQK(0, 0);
  PREFQK(1, 1);

  for (int c = 0; c < NTILES; ++c) {
    if (c + 7 < NTILES) STAGE((c + 7) & 7);
    asm volatile("s_waitcnt vmcnt(15)" ::: "memory");
    const int sofs = (c & 7) * 64;
    PREFQK(2, 2); FENCE; STEPX(0, 0);
    PREFQK(3, 3); FENCE; STEPX(1, 1);
    PREFQK(0, 4); FENCE; STEPX(2, 2);
    PREFQK(1, 5); FENCE; STEPX(3, 3);
    PREFQK(2, 6); FENCE; STEPX(0, 4);
    PREFQK(3, 7); FENCE; STEPX(1, 5);
    PREFQK(0, 8); FENCE; STEPX(2, 6);
    PREFQK(1, 9); FENCE; STEPX(3, 7);
    qp += 8 * SQK; kp += 8 * SQK;
  }
#undef STAGE
#undef PREFQK
#undef FENCE
#undef STEPX
}

// ---------------- gated RMSNorm + silu(gate) -> bf16 ----------------
__global__ __launch_bounds__(256) void post_kernel(
    const float* __restrict__ o, const unsigned short* __restrict__ Y1,
    const float* __restrict__ gw, unsigned short* __restrict__ og)
{
  const int t = blockIdx.x;
  const int tid = threadIdx.x;
  const int e = tid * 8;       // head = tid/32, dv = e&255
  float4 v0 = *(const float4*)(o + (size_t)t * NV_ + e);
  float4 v1 = *(const float4*)(o + (size_t)t * NV_ + e + 4);
  float v[8] = { v0.x, v0.y, v0.z, v0.w, v1.x, v1.y, v1.z, v1.w };
  float ss = 0.f;
  #pragma unroll
  for (int m = 0; m < 8; ++m) ss += v[m] * v[m];
  ss = redsum32(ss);
  float rms = rsqrtf(ss * (1.f / 256.f) + 1e-5f);
  int4 graw = *(const int4*)(Y1 + (size_t)t * N1_ + 4096 + e);
  unsigned int gu[4] = { (unsigned)graw.x, (unsigned)graw.y, (unsigned)graw.z, (unsigned)graw.w };
  float gv[8] = { bflo(gu[0]), bfhi(gu[0]), bflo(gu[1]), bfhi(gu[1]),
                  bflo(gu[2]), bfhi(gu[2]), bflo(gu[3]), bfhi(gu[3]) };
  const int dv = e & 255;
  float res[8];
  #pragma unroll
  for (int m = 0; m < 8; ++m) res[m] = v[m] * rms * gw[dv + m] * siluf(gv[m]);
  int4 outv;
  outv.x = (int)pack2(res[0], res[1]);
  outv.y = (int)pack2(res[2], res[3]);
  outv.z = (int)pack2(res[4], res[5]);
  outv.w = (int)pack2(res[6], res[7]);
  *(int4*)(og + (size_t)t * NV_ + e) = outv;
}

extern "C" void kernel_launch(void* const* d_in, const int* in_sizes, int n_in,
                              void* d_out, int out_size, void* d_ws, size_t ws_size,
                              hipStream_t stream)
{
  (void)in_sizes; (void)n_in; (void)out_size;
  const float* x     = (const float*)d_in[0];
  const float* Wq    = (const float*)d_in[1];
  const float* Wk    = (const float*)d_in[2];
  const float* Wv    = (const float*)d_in[3];
  const float* Wb    = (const float*)d_in[4];
  const float* Wa    = (const float*)d_in[5];
  const float* Wg    = (const float*)d_in[6];
  const float* Wo    = (const float*)d_in[7];
  const float* cq    = (const float*)d_in[8];
  const float* ck    = (const float*)d_in[9];
  const float* cv    = (const float*)d_in[10];
  const float* A_log = (const float*)d_in[11];
  const float* dtb   = (const float*)d_in[12];
  const float* gw    = (const float*)d_in[13];

  // ---- workspace layout with lifetime-based aliasing (peak ~232.5 MiB) ----
  // Region R1 [0, 128MiB):
  //   phase A (cast/transpose/gemm1): xb [0,32MiB) + Wct [32,56MiB)
  //   phase B (conv/delta):           qf [0,32MiB) + kf [32,64MiB) + vf/ov [64,128MiB)
  //   phase C (post/gemm2):           og [0,32MiB)  (qf dead)
  // Then: Wot (8MiB), bg (512KiB), Y1 (96MiB). Ordering guarantees delta's
  // prefetch over-reads of qf/kf land in the next live buffer.
  char* ws = (char*)d_ws;
  const size_t SZ_XB  = (size_t)BT_ * D_ * 2;       // 32 MiB
  const size_t SZ_WCT = (size_t)N1_ * D_ * 2;       // 24 MiB
  const size_t SZ_QF  = (size_t)BT_ * NQK_ * 4;     // 32 MiB
  const size_t SZ_KF  = (size_t)BT_ * NQK_ * 4;     // 32 MiB
  const size_t SZ_VF  = (size_t)BT_ * NV_ * 4;      // 64 MiB
  const size_t SZ_R1a = SZ_XB + SZ_WCT;
  const size_t SZ_R1b = SZ_QF + SZ_KF + SZ_VF;
  const size_t SZ_R1  = (SZ_R1a > SZ_R1b) ? SZ_R1a : SZ_R1b;
  const size_t SZ_WOT = (size_t)D_ * D_ * 2;        // 8 MiB
  const size_t SZ_BG  = (size_t)BT_ * H_ * 8;       // 512 KiB (float2)
  const size_t SZ_Y1  = (size_t)BT_ * N1_ * 2;      // 96 MiB

  const size_t OFF_WOT = SZ_R1;
  const size_t OFF_BG  = OFF_WOT + SZ_WOT;
  const size_t OFF_Y1  = OFF_BG + SZ_BG;
  const size_t WS_NEEDED = OFF_Y1 + SZ_Y1;
  if (ws_size < WS_NEEDED) return;   // diagnostic: absmax == ref-max ==> ws too small

  unsigned short* xb  = (unsigned short*)(ws);                 // phase A
  unsigned short* Wct = (unsigned short*)(ws + SZ_XB);         // phase A
  float* qf = (float*)(ws);                                    // phase B
  float* kf = (float*)(ws + SZ_QF);                            // phase B
  float* vf = (float*)(ws + SZ_QF + SZ_KF);                    // phase B/C (ov aliases)
  float* ov = vf;
  unsigned short* og  = (unsigned short*)(ws);                 // phase C
  unsigned short* Wot = (unsigned short*)(ws + OFF_WOT);
  float* bg   = (float*)(ws + OFF_BG);
  unsigned short* Y1  = (unsigned short*)(ws + OFF_Y1);

  cast_x_kernel<<<(BT_ * D_) / 1024, 256, 0, stream>>>(x, xb);
  dim3 tb(32, 8);
  transpose_cast<<<dim3(1024/32, 2048/32), tb, 0, stream>>>(Wq, Wct, 2048, 1024);
  transpose_cast<<<dim3(1024/32, 2048/32), tb, 0, stream>>>(Wk, Wct + (size_t)1024 * 2048, 2048, 1024);
  transpose_cast<<<dim3(2048/32, 2048/32), tb, 0, stream>>>(Wv, Wct + (size_t)2048 * 2048, 2048, 2048);
  transpose_cast<<<dim3(2048/32, 2048/32), tb, 0, stream>>>(Wg, Wct + (size_t)4096 * 2048, 2048, 2048);
  transpose_cast<<<dim3(2048/32, 2048/32), tb, 0, stream>>>(Wo, Wot, 2048, 2048);

  gemm_kernel<1><<<dim3(N1_/128, BT_/128), 256, 0, stream>>>(xb, Wct, Y1, BT_, N1_, D_);
  beta_g_kernel<<<BT_, 256, 0, stream>>>(x, Wb, Wa, A_log, dtb, bg);
  conv_kernel<<<BT_, 256, 0, stream>>>(Y1, cq, ck, cv, qf, kf, vf);
  delta_kernel<<<B_ * H_ * (DV_/4), 64, 0, stream>>>(qf, kf, vf, bg, ov);
  post_kernel<<<BT_, 256, 0, stream>>>(ov, Y1, gw, og);
  gemm_kernel<0><<<dim3(D_/128, BT_/128), 256, 0, stream>>>(og, Wot, d_out, BT_, D_, D_);
}